// Round 4
// baseline (29.260 us; speedup 1.0000x reference)
//
#include <hip/hip_runtime.h>

// Lanczos-4 8x upsample (4,2,256,256) -> (4,2,2048,2048), fully collapsed.
//
// Exact scale 8 => 8 weight phases; 9 taps span <=2 source rows/cols; the
// nearest-gather replication collapses the whole operator to a 2x2 stencil:
//   out[i,j] = va(i&7)*H(r0) + vb(i&7)*H(r1),  H(r) = wa(j&7)*I[r][c0] + wb(j&7)*I[r][c1]
// with r0=(i-4)>>3, c0=(j-4)>>3 (reflection at edges collapses to a single
// col/row with the full tap sum as weight).
//
// R4: same as R3 but nontemporal stores via clang ext_vector_type (HIP's
// float4 class type is rejected by __builtin_nontemporal_store).

typedef float float4n __attribute__((ext_vector_type(4)));

// wa (left-column weight), per phase 0..7
#define WA0 0.0f
#define WA1 -0.03041110f
#define WA2 0.02753266f
#define WA3 -0.00827163f
#define WA4 1.00243180f
#define WA5 1.01040147f
#define WA6 0.97375330f
#define WA7 1.03080550f
// wb (right-column weight)
#define WB0 1.0f
#define WB1 1.02991210f
#define WB2 0.97065798f
#define WB3 1.00472265f
#define WB4 -0.00765906f
#define WB5 -0.01652347f
#define WB6 0.02047608f
#define WB7 -0.03455115f
// full tap sum (edge / reflected case: all 9 taps hit one source col/row)
#define WS0 1.0f
#define WS1 0.99950100f
#define WS2 0.99819064f
#define WS3 0.99645102f
#define WS4 0.99477274f
#define WS5 0.99387800f
#define WS6 0.99422938f
#define WS7 0.99625435f

__global__ __launch_bounds__(512) void lanczos_up8_kernel(
    const float* __restrict__ img, float* __restrict__ out)
{
    // grid: bid = bc(8) * 256 + t(256); block covers all 2048 cols of 8 rows
    int bid  = blockIdx.x;
    int t    = bid & 255;        // source row / output row-group
    int bc   = bid >> 8;         // fused batch*channel 0..7
    int v    = threadIdx.x;      // 4-col output group, 0..511

    int P = v & 1;               // parity: phases 0..3 (P=0) or 4..7 (P=1)
    int m = v >> 1;              // source column group

    bool eL = (v == 0);          // j=0..3   : all taps reflect onto col 0
    bool eR = (v == 511);        // j=2044..7: all taps reflect onto col 255

    // horizontal weights for this lane's 4 phases (all-constant selects)
    float a0 = P ? WA4 : WA0, b0 = P ? WB4 : WB0;
    float a1 = P ? WA5 : WA1, b1 = P ? WB5 : WB1;
    float a2 = P ? WA6 : WA2, b2 = P ? WB6 : WB2;
    float a3 = P ? WA7 : WA3, b3 = P ? WB7 : WB3;
    if (eL) { a0 = WS0; a1 = WS1; a2 = WS2; a3 = WS3; b0 = b1 = b2 = b3 = 0.f; }
    if (eR) { a0 = WS4; a1 = WS5; a2 = WS6; a3 = WS7; b0 = b1 = b2 = b3 = 0.f; }

    int c0 = P ? m : m - 1;
    if (eL) c0 = 0;
    if (eR) c0 = 255;
    int c1 = (eL || eR) ? c0 : c0 + 1;

    int rm = t > 0   ? t - 1 : 0;    // block-uniform row indices (clamped)
    int rp = t < 255 ? t + 1 : 255;

    const float* base = img + bc * 65536;
    float i00 = base[rm * 256 + c0], i01 = base[rm * 256 + c1];
    float i10 = base[t  * 256 + c0], i11 = base[t  * 256 + c1];
    float i20 = base[rp * 256 + c0], i21 = base[rp * 256 + c1];

    // horizontally-filtered values for 3 source rows x 4 output cols
    float h00 = a0*i00 + b0*i01, h01 = a1*i00 + b1*i01, h02 = a2*i00 + b2*i01, h03 = a3*i00 + b3*i01;
    float h10 = a0*i10 + b0*i11, h11 = a1*i10 + b1*i11, h12 = a2*i10 + b2*i11, h13 = a3*i10 + b3*i11;
    float h20 = a0*i20 + b0*i21, h21 = a1*i20 + b1*i21, h22 = a2*i20 + b2*i21, h23 = a3*i20 + b3*i21;

    bool eT = (t == 0);     // rows 0..3   : all taps reflect onto row 0
    bool eB = (t == 255);   // rows 2044..7: all taps reflect onto row 255

    float* op = out + (size_t)bc * (2048 * 2048)
                    + (size_t)(t << 3) * 2048 + (v << 2);

    float va, vb; float4n o;
    // s<4: rows (t-1, t) -> (h0*, h1*);  s>=4: rows (t, t+1) -> (h1*, h2*)
#define EMIT(S, WAs, WBs, WSs, HX0,HX1,HX2,HX3, HY0,HY1,HY2,HY3, EDGE)   \
    va = (EDGE) ? WSs : WAs;  vb = (EDGE) ? 0.f : WBs;                   \
    o.x = va*HX0 + vb*HY0;  o.y = va*HX1 + vb*HY1;                       \
    o.z = va*HX2 + vb*HY2;  o.w = va*HX3 + vb*HY3;                       \
    __builtin_nontemporal_store(o, reinterpret_cast<float4n*>(op + S * 2048));

    EMIT(0, WA0, WB0, WS0, h00,h01,h02,h03, h10,h11,h12,h13, eT)
    EMIT(1, WA1, WB1, WS1, h00,h01,h02,h03, h10,h11,h12,h13, eT)
    EMIT(2, WA2, WB2, WS2, h00,h01,h02,h03, h10,h11,h12,h13, eT)
    EMIT(3, WA3, WB3, WS3, h00,h01,h02,h03, h10,h11,h12,h13, eT)
    EMIT(4, WA4, WB4, WS4, h10,h11,h12,h13, h20,h21,h22,h23, eB)
    EMIT(5, WA5, WB5, WS5, h10,h11,h12,h13, h20,h21,h22,h23, eB)
    EMIT(6, WA6, WB6, WS6, h10,h11,h12,h13, h20,h21,h22,h23, eB)
    EMIT(7, WA7, WB7, WS7, h10,h11,h12,h13, h20,h21,h22,h23, eB)
#undef EMIT
}

extern "C" void kernel_launch(void* const* d_in, const int* in_sizes, int n_in,
                              void* d_out, int out_size, void* d_ws, size_t ws_size,
                              hipStream_t stream) {
    const float* img = (const float*)d_in[0];
    float* out = (float*)d_out;
    dim3 grid(2048), block(512);
    hipLaunchKernelGGL(lanczos_up8_kernel, grid, block, 0, stream, img, out);
}

// Round 5
// 26.349 us; speedup vs baseline: 1.1105x; 1.1105x over previous
//
#include <hip/hip_runtime.h>

// Lanczos-4 8x upsample (4,2,256,256) -> (4,2,2048,2048), fully collapsed.
//
// Exact scale 8 => 8 weight phases; 9 taps span <=2 source rows/cols; the
// nearest-gather replication collapses the whole operator to a 2x2 stencil:
//   out[i,j] = va(i&7)*H(r0) + vb(i&7)*H(r1),  H(r) = wa(j&7)*I[r][c0] + wb(j&7)*I[r][c1]
// with r0=(i-4)>>3, c0=(j-4)>>3 (reflection at edges collapses to a single
// col/row with the full tap sum as weight).
//
// R5: full-width 512-thread blocks (one contiguous 64 KB span per block),
// REGULAR float4 stores (R4's nontemporal stores regressed 26.7 -> 29.3 us;
// single-variable revert to attribute).

// wa (left-column weight), per phase 0..7
#define WA0 0.0f
#define WA1 -0.03041110f
#define WA2 0.02753266f
#define WA3 -0.00827163f
#define WA4 1.00243180f
#define WA5 1.01040147f
#define WA6 0.97375330f
#define WA7 1.03080550f
// wb (right-column weight)
#define WB0 1.0f
#define WB1 1.02991210f
#define WB2 0.97065798f
#define WB3 1.00472265f
#define WB4 -0.00765906f
#define WB5 -0.01652347f
#define WB6 0.02047608f
#define WB7 -0.03455115f
// full tap sum (edge / reflected case: all 9 taps hit one source col/row)
#define WS0 1.0f
#define WS1 0.99950100f
#define WS2 0.99819064f
#define WS3 0.99645102f
#define WS4 0.99477274f
#define WS5 0.99387800f
#define WS6 0.99422938f
#define WS7 0.99625435f

__global__ __launch_bounds__(512) void lanczos_up8_kernel(
    const float* __restrict__ img, float* __restrict__ out)
{
    // grid: bid = bc(8) * 256 + t(256); block covers all 2048 cols of 8 rows
    int bid  = blockIdx.x;
    int t    = bid & 255;        // source row / output row-group
    int bc   = bid >> 8;         // fused batch*channel 0..7
    int v    = threadIdx.x;      // 4-col output group, 0..511

    int P = v & 1;               // parity: phases 0..3 (P=0) or 4..7 (P=1)
    int m = v >> 1;              // source column group

    bool eL = (v == 0);          // j=0..3   : all taps reflect onto col 0
    bool eR = (v == 511);        // j=2044..7: all taps reflect onto col 255

    // horizontal weights for this lane's 4 phases (all-constant selects)
    float a0 = P ? WA4 : WA0, b0 = P ? WB4 : WB0;
    float a1 = P ? WA5 : WA1, b1 = P ? WB5 : WB1;
    float a2 = P ? WA6 : WA2, b2 = P ? WB6 : WB2;
    float a3 = P ? WA7 : WA3, b3 = P ? WB7 : WB3;
    if (eL) { a0 = WS0; a1 = WS1; a2 = WS2; a3 = WS3; b0 = b1 = b2 = b3 = 0.f; }
    if (eR) { a0 = WS4; a1 = WS5; a2 = WS6; a3 = WS7; b0 = b1 = b2 = b3 = 0.f; }

    int c0 = P ? m : m - 1;
    if (eL) c0 = 0;
    if (eR) c0 = 255;
    int c1 = (eL || eR) ? c0 : c0 + 1;

    int rm = t > 0   ? t - 1 : 0;    // block-uniform row indices (clamped)
    int rp = t < 255 ? t + 1 : 255;

    const float* base = img + bc * 65536;
    float i00 = base[rm * 256 + c0], i01 = base[rm * 256 + c1];
    float i10 = base[t  * 256 + c0], i11 = base[t  * 256 + c1];
    float i20 = base[rp * 256 + c0], i21 = base[rp * 256 + c1];

    // horizontally-filtered values for 3 source rows x 4 output cols
    float h00 = a0*i00 + b0*i01, h01 = a1*i00 + b1*i01, h02 = a2*i00 + b2*i01, h03 = a3*i00 + b3*i01;
    float h10 = a0*i10 + b0*i11, h11 = a1*i10 + b1*i11, h12 = a2*i10 + b2*i11, h13 = a3*i10 + b3*i11;
    float h20 = a0*i20 + b0*i21, h21 = a1*i20 + b1*i21, h22 = a2*i20 + b2*i21, h23 = a3*i20 + b3*i21;

    bool eT = (t == 0);     // rows 0..3   : all taps reflect onto row 0
    bool eB = (t == 255);   // rows 2044..7: all taps reflect onto row 255

    float* op = out + (size_t)bc * (2048 * 2048)
                    + (size_t)(t << 3) * 2048 + (v << 2);

    float va, vb; float4 o;
    // s<4: rows (t-1, t) -> (h0*, h1*);  s>=4: rows (t, t+1) -> (h1*, h2*)
#define EMIT(S, WAs, WBs, WSs, HX0,HX1,HX2,HX3, HY0,HY1,HY2,HY3, EDGE)   \
    va = (EDGE) ? WSs : WAs;  vb = (EDGE) ? 0.f : WBs;                   \
    o.x = va*HX0 + vb*HY0;  o.y = va*HX1 + vb*HY1;                       \
    o.z = va*HX2 + vb*HY2;  o.w = va*HX3 + vb*HY3;                       \
    *reinterpret_cast<float4*>(op + S * 2048) = o;

    EMIT(0, WA0, WB0, WS0, h00,h01,h02,h03, h10,h11,h12,h13, eT)
    EMIT(1, WA1, WB1, WS1, h00,h01,h02,h03, h10,h11,h12,h13, eT)
    EMIT(2, WA2, WB2, WS2, h00,h01,h02,h03, h10,h11,h12,h13, eT)
    EMIT(3, WA3, WB3, WS3, h00,h01,h02,h03, h10,h11,h12,h13, eT)
    EMIT(4, WA4, WB4, WS4, h10,h11,h12,h13, h20,h21,h22,h23, eB)
    EMIT(5, WA5, WB5, WS5, h10,h11,h12,h13, h20,h21,h22,h23, eB)
    EMIT(6, WA6, WB6, WS6, h10,h11,h12,h13, h20,h21,h22,h23, eB)
    EMIT(7, WA7, WB7, WS7, h10,h11,h12,h13, h20,h21,h22,h23, eB)
#undef EMIT
}

extern "C" void kernel_launch(void* const* d_in, const int* in_sizes, int n_in,
                              void* d_out, int out_size, void* d_ws, size_t ws_size,
                              hipStream_t stream) {
    const float* img = (const float*)d_in[0];
    float* out = (float*)d_out;
    dim3 grid(2048), block(512);
    hipLaunchKernelGGL(lanczos_up8_kernel, grid, block, 0, stream, img, out);
}